// Round 16
// baseline (434.069 us; speedup 1.0000x reference)
//
#include <hip/hip_runtime.h>

// DGMC top-k correspondence, MI355X — bf16 MFMA candidate GEMM + f64 refine.
// r16: GEMM moved from 32x32x16 to 16x16x32 MFMA. Rationale: the 32x32 shape's
// 64-reg B-panel + 16-reg acc (~145 unified live regs) pinned the kernel at
// 3 blocks/CU — every occupancy/pipelining attempt spilled (r5/r6/r11/r14).
// 16x16x32 halves both (32-reg B-panel, 2x4-reg accs) -> ~90 live regs ->
// launch_bounds(256,4) with real margin -> 4 blocks/CU, 50% occupancy, and
// the dependent MFMA chains halve (2x8). MFMA floor 44->49 us (16x16 rate).
// Phase 0: convert BOTH h_t arrays fp32 -> bf16 in one dispatch, granule-swizzled
//          (phys granule g holds logical g^(row&31)).
// Phase 1: S^T tiles: A = h_t (16 t-rows x 32 k) from LDS, B = h_s (32 k x 16
//          s-cols) persistent in regs. C/D (m89-verified): col=lane&15,
//          row=(lane>>4)*4+reg. Per-lane top-10 as SORTED PACKED uints:
//          key = bits(S+256.f) & VMASK | (rd<<3|r); bias via MFMA C-init.
//          Chain = (srow, q=lane>>4, p): CH = 4*Pt chains/row.
//          Pt=14 (r9: bigger Pt replicates the B-panel prologue). PS=736 ->
//          rdbits=5 -> 24 value bits (quantum 2^-7; r8's 0.5 quantum failed).
// Phase 2: per-row merge of packed chains -> top-12 (key,t), payload ripple-insert.
// Phase 3: f64 re-eval, one block/row, coalesced 256B gathers, lane-parallel
//          rank, softmax, scatter write.

typedef __attribute__((ext_vector_type(8)))  short bf16x8;
typedef __attribute__((ext_vector_type(4)))  float f32x4;
typedef __attribute__((ext_vector_type(8)))  unsigned short u16x8;

#define K_TOP 10
#define CAND_M 12
#define CDIM 256
#define LDS_HALF 8192   // shorts per 32x256 tile buffer (16 KB)

#define GLD_LDS(src, dst) \
    __builtin_amdgcn_global_load_lds((const __attribute__((address_space(1))) void*)(src), \
                                     (__attribute__((address_space(3))) void*)(dst), 16, 0, 0)

__device__ __forceinline__ unsigned short f2bf(float f) {
    unsigned u = __float_as_uint(f);
    u += 0x7fffu + ((u >> 16) & 1u);      // RNE
    return (unsigned short)(u >> 16);
}

__device__ __forceinline__ unsigned umax2(unsigned a, unsigned b) { return a > b ? a : b; }
__device__ __forceinline__ unsigned umax3(unsigned a, unsigned b, unsigned c) {
    return umax2(umax2(a, b), c);          // fuses to v_max3_u32
}

__device__ __forceinline__ unsigned umax8(const unsigned (&p)[8]) {
    return umax2(umax2(umax3(p[0], p[1], p[2]), umax3(p[3], p[4], p[5])),
                 umax3(p[6], p[7], p[0]));
}

// Branchless ripple-insert of v into descending-sorted tv. No-op when v <= tv[K-1].
template <int K>
__device__ __forceinline__ void sorted_insert(unsigned (&tv)[K], unsigned v) {
    bool m[K];
#pragma unroll
    for (int q = 0; q < K; ++q) m[q] = tv[q] >= v;
    unsigned nv[K];
    nv[0] = m[0] ? tv[0] : v;
#pragma unroll
    for (int q = 1; q < K; ++q)
        nv[q] = m[q] ? tv[q] : (m[q - 1] ? v : tv[q - 1]);
#pragma unroll
    for (int q = 0; q < K; ++q) tv[q] = nv[q];
}

// Payload-carrying variant: key array + t array stay in registers (full unroll).
__device__ __forceinline__ void sorted_insert2(unsigned (&tk)[CAND_M], int (&tt)[CAND_M],
                                               unsigned k, int t) {
    bool m[CAND_M];
#pragma unroll
    for (int q = 0; q < CAND_M; ++q) m[q] = tk[q] >= k;
    unsigned nk[CAND_M]; int nt[CAND_M];
    nk[0] = m[0] ? tk[0] : k;
    nt[0] = m[0] ? tt[0] : t;
#pragma unroll
    for (int q = 1; q < CAND_M; ++q) {
        nk[q] = m[q] ? tk[q] : (m[q - 1] ? k : tk[q - 1]);
        nt[q] = m[q] ? tt[q] : (m[q - 1] ? t : tt[q - 1]);
    }
#pragma unroll
    for (int q = 0; q < CAND_M; ++q) { tk[q] = nk[q]; tt[q] = nt[q]; }
}

// ---------- Phase 0: fp32 -> bf16 with per-row granule XOR swizzle (both arrays) ----------
__global__ void conv_swz2(const float* __restrict__ inE, unsigned short* __restrict__ outE,
                          const float* __restrict__ inR, unsigned short* __restrict__ outR,
                          int N)
{
    int gid = blockIdx.x * blockDim.x + threadIdx.x;
    int half = N * 32;
    const float* in = (gid < half) ? inE : inR;
    unsigned short* out = (gid < half) ? outE : outR;
    int g2 = (gid < half) ? gid : gid - half;
    int row = g2 >> 5, gl = g2 & 31;
    if (row >= N) return;
    const float4* src = (const float4*)(in + (size_t)row * CDIM + gl * 8);
    float4 a0 = src[0], a1 = src[1];
    u16x8 o;
    o[0] = f2bf(a0.x); o[1] = f2bf(a0.y); o[2] = f2bf(a0.z); o[3] = f2bf(a0.w);
    o[4] = f2bf(a1.x); o[5] = f2bf(a1.y); o[6] = f2bf(a1.z); o[7] = f2bf(a1.w);
    *(u16x8*)(out + (size_t)row * CDIM + ((gl ^ (row & 31)) * 8)) = o;
}

// ---------- Phase 1: MFMA GEMM + per-lane packed top-10 ----------
__device__ __forceinline__ void stage32(const unsigned short* __restrict__ htb,
                                        short* ldsbuf, int tbase, int Nt,
                                        int tid, int wbase) {
#pragma unroll
    for (int it = 0; it < 4; ++it) {
        int pp = it * 256 + tid;
        int rr = pp >> 5, gg = pp & 31;
        int grow = tbase + rr; grow = grow < Nt ? grow : Nt - 1;
        GLD_LDS(htb + (size_t)grow * CDIM + gg * 8, ldsbuf + (it * 256 + wbase) * 8);
    }
}

// block = 256 thr = 4 waves; wave w owns 16 s-cols (block spans 64 s).
// Lane (l4 = lane&15, q = lane>>4): s-col l4's chain-q, k-quarter q.
// LDS: 2 x (32 t-rows x 256 bf16) = 32 KB double buffer.
__global__ __launch_bounds__(256, 4) void topk_mfma(
    const float* __restrict__ ehs, const float* __restrict__ rhs_,
    const unsigned short* __restrict__ ehtb, const unsigned short* __restrict__ rhtb,
    unsigned* __restrict__ partials, int Ns, int Nt, int Pt, int SB, int PS,
    unsigned VMASK)
{
    __shared__ short ldsT[2 * LDS_HALF];

    const int tid = threadIdx.x;
    const int w = tid >> 6, lane = tid & 63;
    const int l4 = lane & 15, q = lane >> 4;
    const int wbase = tid & ~63;
    const int CH = 4 * Pt;

    const int bid  = blockIdx.x;
    const int prob = bid / (Pt * SB);
    const int rem  = bid % (Pt * SB);
    const int p    = rem / SB, sb = rem % SB;

    const float* hs = prob ? rhs_ : ehs;
    const unsigned short* htb = prob ? rhtb : ehtb;

    const int srow = sb * 64 + w * 16 + l4;
    const int srd  = srow < Ns ? srow : Ns - 1;

    // B-panel: h_s[srd][kk*32 + q*8 + j], j=0..7 -> 8 frags (32 regs), persistent.
    // (B lane mapping for 16x16x32: col = lane&15, k = (lane>>4)*8 + j.)
    bf16x8 b[8];
#pragma unroll
    for (int kk = 0; kk < 8; ++kk) {
        const float4* sp = (const float4*)(hs + (size_t)srd * CDIM + kk * 32 + q * 8);
        float4 f0 = sp[0], f1 = sp[1];
        bf16x8 t;
        t[0] = (short)f2bf(f0.x); t[1] = (short)f2bf(f0.y);
        t[2] = (short)f2bf(f0.z); t[3] = (short)f2bf(f0.w);
        t[4] = (short)f2bf(f1.x); t[5] = (short)f2bf(f1.y);
        t[6] = (short)f2bf(f1.z); t[7] = (short)f2bf(f1.w);
        b[kk] = t;
    }

    const int t0 = p * PS;
    const int t1 = min(t0 + PS, Nt);

    unsigned tvp[K_TOP];
#pragma unroll
    for (int qq = 0; qq < K_TOP; ++qq) tvp[qq] = 0u;

    const int rounds = (t1 > t0) ? ((t1 - t0 + 31) >> 5) : 0;

    if (rounds > 0) {
        stage32(htb, ldsT, t0, Nt, tid, wbase);
        __syncthreads();

        for (int rd = 0; rd < rounds; ++rd) {
            const int cur = rd & 1;
            const int tb  = t0 + rd * 32;
            if (rd + 1 < rounds)
                stage32(htb, ldsT + (cur ^ 1) * LDS_HALF, tb + 32, Nt, tid, wbase);

            const bool guard = (tb + 32 > t1);
            // A-frag rows: tile rows r0 = l4 (acc0), r1 = 16+l4 (acc1);
            // granule for kstep kk = (kk*4 + q) ^ row (conv pre-swizzle undone).
            const short* base0 = ldsT + cur * LDS_HALF + l4 * CDIM;
            const short* base1 = base0 + 16 * CDIM;
            f32x4 acc0, acc1;
#pragma unroll
            for (int r = 0; r < 4; ++r) { acc0[r] = 256.0f; acc1[r] = 256.0f; }
#pragma unroll
            for (int kk = 0; kk < 8; ++kk) {
                bf16x8 a0 = *(const bf16x8*)(base0 + (((kk * 4 + q) ^ l4) * 8));
                acc0 = __builtin_amdgcn_mfma_f32_16x16x32_bf16(a0, b[kk], acc0, 0, 0, 0);
                bf16x8 a1 = *(const bf16x8*)(base1 + (((kk * 4 + q) ^ (16 + l4)) * 8));
                acc1 = __builtin_amdgcn_mfma_f32_16x16x32_bf16(a1, b[kk], acc1, 0, 0, 0);
            }
            // ---- packed scan: one (s-col, q) chain per lane, 8 t-values ----
            // t-local(r) = (r&3) + q*4 + (r>>2)*16  (C/D row = q*4 + reg, m89).
            const unsigned ibase = (unsigned)(rd << 3);
            unsigned pu[8];
#pragma unroll
            for (int r = 0; r < 4; ++r) {
                pu[r]     = (__float_as_uint(acc0[r]) & VMASK) | (ibase + (unsigned)r);
                pu[4 + r] = (__float_as_uint(acc1[r]) & VMASK) | (ibase + (unsigned)(4 + r));
            }
            if (guard) {
#pragma unroll
                for (int r = 0; r < 8; ++r) {
                    int t = tb + (r & 3) + q * 4 + (r >> 2) * 16;
                    if (t >= t1) pu[r] = 0u;
                }
            }
            unsigned mx = umax8(pu);
            while (__any((int)(mx > tvp[K_TOP - 1]))) {
                sorted_insert<K_TOP>(tvp, mx);   // no-op for lanes with mx <= tvp[9]
#pragma unroll
                for (int r = 0; r < 8; ++r)
                    pu[r] = (pu[r] == mx) ? 0u : pu[r];
                mx = umax8(pu);
            }
            __syncthreads();
        }
    }

    // chain write: RAW keys, chain = p*4 + q, layout [prob][chain][q10][Ns]
    if (srow < Ns) {
        unsigned* wp = partials + ((size_t)(prob * CH + (p * 4 + q)) * K_TOP) * Ns + srow;
#pragma unroll
        for (int qq = 0; qq < K_TOP; ++qq) wp[(size_t)qq * Ns] = tvp[qq];
    }
}

// ---------- Phase 2: merge packed chains -> top-12 candidate t's ----------
__global__ void topk_mergecand(const unsigned* __restrict__ partials, int* __restrict__ cand,
                               int Ns, int CH, int PS, unsigned rdMask)
{
    int g = blockIdx.x * blockDim.x + threadIdx.x;
    if (g >= 2 * Ns) return;
    const int prob = g >= Ns ? 1 : 0;
    const int row  = g - prob * Ns;
    const unsigned* src = partials + ((size_t)prob * CH * K_TOP) * Ns + row;

    unsigned tvk[CAND_M]; int tvt[CAND_M];
#pragma unroll
    for (int q = 0; q < CAND_M; ++q) { tvk[q] = 0u; tvt[q] = 0; }

    for (int c = 0; c < CH; ++c) {
        // chain c: partition p = c>>2, k-quarter q = c&3
        const int tbase = (c >> 2) * PS + (c & 3) * 4;
#pragma unroll
        for (int q = 0; q < K_TOP; ++q) {
            unsigned k = src[(size_t)(c * K_TOP + q) * Ns];
            if (k > tvk[CAND_M - 1]) {
                unsigned rd = (k >> 3) & rdMask;
                unsigned r  = k & 7u;
                int t = tbase + (int)rd * 32 + (int)((r & 3) + (r >> 2) * 16);
                sorted_insert2(tvk, tvt, k, t);
            }
        }
    }
    int* dst = cand + (size_t)g * CAND_M;
#pragma unroll
    for (int q = 0; q < CAND_M; ++q) dst[q] = tvt[q];
}

// ---------- Phase 3: f64 refine, coalesced, one block per row ----------
// tid = m*16 + c: candidate m (0..15, active m<CAND_M), chunk c (0..15). Lane c
// reads float4 granules {c, c+16, c+32, c+48} -> each load instruction covers a
// contiguous 256 B of one row. f64 accumulate, shfl reduce over c, LDS rank+softmax.
__global__ __launch_bounds__(256) void topk_refine(
    const float* __restrict__ ehs, const float* __restrict__ eht,
    const float* __restrict__ rhs_, const float* __restrict__ rht,
    const int* __restrict__ cand, float* __restrict__ out, int Ns)
{
    __shared__ double svd[CAND_M];
    __shared__ int    sci[CAND_M];

    const int wid = blockIdx.x;               // one row per block, grid = 2*Ns
    const int tid = threadIdx.x;
    const int m = tid >> 4, c = tid & 15;

    const int prob = wid < Ns ? 0 : 1;
    const int row  = prob ? (wid - Ns) : wid;
    const float* hs = prob ? rhs_ : ehs;
    const float* ht = prob ? rht  : eht;

    if (m < CAND_M) {
        const int t = cand[(size_t)wid * CAND_M + m];
        const float4* ap = (const float4*)(hs + (size_t)row * CDIM);
        const float4* bp = (const float4*)(ht + (size_t)t   * CDIM);

        double s = 0.0;
#pragma unroll
        for (int i = 0; i < 4; ++i) {
            float4 av = ap[c + 16 * i];
            float4 bv = bp[c + 16 * i];
            s += (double)av.x * (double)bv.x + (double)av.y * (double)bv.y
               + (double)av.z * (double)bv.z + (double)av.w * (double)bv.w;
        }
        // 16-lane group (same m, c = low 4 bits): butterfly over c
        s += __shfl_xor(s, 1, 64);
        s += __shfl_xor(s, 2, 64);
        s += __shfl_xor(s, 4, 64);
        s += __shfl_xor(s, 8, 64);
        if (c == 0) { svd[m] = s; sci[m] = t; }
    }
    __syncthreads();

    if (tid < 16) {                           // all 16 lanes run the butterfly
        const bool act = tid < CAND_M;
        const double sm = act ? svd[tid] : -1.0e300;
        const int    tm = act ? sci[tid] : 0x7FFFFFFF;
        int rank = 0; double vmax = -1.0e300;
#pragma unroll
        for (int j = 0; j < CAND_M; ++j) {
            double vj = svd[j]; int cj = sci[j];
            bool better = (vj > sm) || (vj == sm && cj < tm);
            rank += better ? 1 : 0;
            vmax = fmax(vmax, vj);
        }
        float ex = (act && rank < K_TOP) ? __expf((float)(sm - vmax)) : 0.f;
        float ssum = ex;
        ssum += __shfl_xor(ssum, 1, 64);
        ssum += __shfl_xor(ssum, 2, 64);
        ssum += __shfl_xor(ssum, 4, 64);
        ssum += __shfl_xor(ssum, 8, 64);      // sum over the 16 lanes (inactive = 0)
        if (act && rank < K_TOP) {
            size_t nsk = (size_t)Ns * K_TOP;
            size_t so  = (size_t)wid * K_TOP;
            out[so + rank] = ex / ssum;
            out[2 * nsk + so + rank] = (float)tm;
        }
    }
}

extern "C" void kernel_launch(void* const* d_in, const int* in_sizes, int n_in,
                              void* d_out, int out_size, void* d_ws, size_t ws_size,
                              hipStream_t stream) {
    (void)n_in; (void)out_size;
    const float* eh_s = (const float*)d_in[0];
    const float* eh_t = (const float*)d_in[1];
    const float* rh_s = (const float*)d_in[2];
    const float* rh_t = (const float*)d_in[3];
    // d_in[4] is k (=10), compile-time constant here.

    const int Ns = in_sizes[0] / CDIM;
    const int Nt = in_sizes[1] / CDIM;
    const int SB = (Ns + 63) / 64;            // 64 s-cols per block

    const size_t htbElems = (size_t)Nt * CDIM;          // per array, ushorts
    const size_t htbBytes = 2 * htbElems * 2;
    const size_t candBytes = (size_t)2 * Ns * CAND_M * sizeof(int);

    // Pt=14 (r9: bigger Pt replicates the B-panel prologue). CH = 4*Pt chains.
    int Pt = 14;
    while (Pt > 1 &&
           htbBytes + (size_t)2 * Ns * (4 * Pt) * K_TOP * sizeof(unsigned) + candBytes > ws_size)
        Pt -= 1;
    const int PS = (int)((((size_t)Nt + Pt - 1) / Pt + 31) & ~(size_t)31);

    // idx-field width: 3 (r) + rdbits, where 2^rdbits >= PS/32. VMASK keeps the rest.
    int rdbits = 0;
    while ((1 << rdbits) < (PS >> 5)) ++rdbits;
    const int IDXB = 3 + rdbits;
    const unsigned VMASK  = ~((1u << IDXB) - 1u);
    const unsigned rdMask = (1u << rdbits) - 1u;

    unsigned short* htb_e = (unsigned short*)d_ws;
    unsigned short* htb_r = htb_e + htbElems;
    unsigned* partials = (unsigned*)(htb_r + htbElems);
    int*  cand = (int*)((char*)partials + (size_t)2 * Ns * (4 * Pt) * K_TOP * sizeof(unsigned));

    dim3 block(256);

    // Phase 0: convert both h_t arrays (swizzled bf16), one dispatch
    int convBlocks = (2 * Nt * 32 + 255) / 256;
    conv_swz2<<<dim3(convBlocks), block, 0, stream>>>(eh_t, htb_e, rh_t, htb_r, Nt);

    // Phase 1: MFMA GEMM + packed top-10 chains
    topk_mfma<<<dim3(2 * Pt * SB), block, 0, stream>>>(eh_s, rh_s, htb_e, htb_r,
                                                       partials, Ns, Nt, Pt, SB, PS,
                                                       VMASK);

    // Phase 2: merge -> candidate t's (decode from chain id + packed rd,r)
    int nrows = 2 * Ns;
    topk_mergecand<<<dim3((nrows + 255) / 256), block, 0, stream>>>(partials, cand,
                                                                    Ns, 4 * Pt, PS, rdMask);

    // Phase 3: f64 refine + softmax + write (one block per row)
    topk_refine<<<dim3(nrows), block, 0, stream>>>(eh_s, eh_t, rh_s, rh_t,
                                                   cand, (float*)d_out, Ns);
}

// Round 17
// 279.032 us; speedup vs baseline: 1.5556x; 1.5556x over previous
//
#include <hip/hip_runtime.h>

// DGMC top-k correspondence, MI355X — bf16 MFMA candidate GEMM + f64 refine.
// r17 = r15 GEMM (verified best: 230 us, all structural levers counter-proven
// closed) + merge FUSED into refine. The standalone merge ran 2e4 threads in 79
// blocks (~1.2 waves/CU, latency-exposed); fused, wave 0 of each refine block
// (2e4 blocks) does a lane-parallel 12-round extract-max over the 28 sorted
// chains, writing candidate t's straight to LDS. Kills one launch + cand trip.
// Phase 0: convert BOTH h_t arrays fp32 -> bf16, one dispatch, granule-swizzled.
// Phase 1: S^T tiles via mfma_f32_32x32x16_bf16 (A=h_t from LDS, B=h_s in regs).
//          Per-lane top-10 as SORTED PACKED uints: key = bits(S+256.f) & VMASK
//          | (rd<<4|r); +256 bias via MFMA C-init; single 16-MFMA acc chain.
//          launch_bounds(256,3) — (256,4)+ spills the 64-reg B-panel
//          (r5/r6/r11); dual-acc skew spills live-across-chain state (r14);
//          16x16x32 shape trades register relief for +40% fixed overhead (r16).
//          Pt=14 (r9: bigger Pt replicates the B-panel prologue, +60 MB fetch).
//          PS=736 -> rdbits=5 -> 23 value bits (quantum 2^-6; r8's 0.5 failed).
// Phase 2 (fused): wave-parallel merge -> top-12 candidate t's in LDS.
// Phase 3: f64 re-eval, coalesced 256B gathers, lane-parallel rank, softmax.

typedef __attribute__((ext_vector_type(8)))  short bf16x8;
typedef __attribute__((ext_vector_type(16))) float f32x16;
typedef __attribute__((ext_vector_type(8)))  unsigned short u16x8;

#define K_TOP 10
#define CAND_M 12
#define CDIM 256

#define GLD_LDS(src, dst) \
    __builtin_amdgcn_global_load_lds((const __attribute__((address_space(1))) void*)(src), \
                                     (__attribute__((address_space(3))) void*)(dst), 16, 0, 0)

__device__ __forceinline__ unsigned short f2bf(float f) {
    unsigned u = __float_as_uint(f);
    u += 0x7fffu + ((u >> 16) & 1u);      // RNE
    return (unsigned short)(u >> 16);
}

__device__ __forceinline__ unsigned umax2(unsigned a, unsigned b) { return a > b ? a : b; }
__device__ __forceinline__ unsigned umax3(unsigned a, unsigned b, unsigned c) {
    return umax2(umax2(a, b), c);          // fuses to v_max3_u32
}

__device__ __forceinline__ unsigned umax16(const unsigned (&p)[16]) {
    unsigned x0 = umax3(p[0],  p[1],  p[2]);
    unsigned x1 = umax3(p[3],  p[4],  p[5]);
    unsigned x2 = umax3(p[6],  p[7],  p[8]);
    unsigned x3 = umax3(p[9],  p[10], p[11]);
    unsigned x4 = umax3(p[12], p[13], p[14]);
    return umax2(umax3(x0, x1, x2), umax3(x3, x4, p[15]));
}

// Branchless ripple-insert of v into descending-sorted tv. No-op when v <= tv[K-1].
template <int K>
__device__ __forceinline__ void sorted_insert(unsigned (&tv)[K], unsigned v) {
    bool m[K];
#pragma unroll
    for (int q = 0; q < K; ++q) m[q] = tv[q] >= v;
    unsigned nv[K];
    nv[0] = m[0] ? tv[0] : v;
#pragma unroll
    for (int q = 1; q < K; ++q)
        nv[q] = m[q] ? tv[q] : (m[q - 1] ? v : tv[q - 1]);
#pragma unroll
    for (int q = 0; q < K; ++q) tv[q] = nv[q];
}

// ---------- Phase 0: fp32 -> bf16 with per-row granule XOR swizzle (both arrays) ----------
__global__ void conv_swz2(const float* __restrict__ inE, unsigned short* __restrict__ outE,
                          const float* __restrict__ inR, unsigned short* __restrict__ outR,
                          int N)
{
    int gid = blockIdx.x * blockDim.x + threadIdx.x;
    int half = N * 32;
    const float* in = (gid < half) ? inE : inR;
    unsigned short* out = (gid < half) ? outE : outR;
    int g2 = (gid < half) ? gid : gid - half;
    int row = g2 >> 5, gl = g2 & 31;
    if (row >= N) return;
    const float4* src = (const float4*)(in + (size_t)row * CDIM + gl * 8);
    float4 a0 = src[0], a1 = src[1];
    u16x8 o;
    o[0] = f2bf(a0.x); o[1] = f2bf(a0.y); o[2] = f2bf(a0.z); o[3] = f2bf(a0.w);
    o[4] = f2bf(a1.x); o[5] = f2bf(a1.y); o[6] = f2bf(a1.z); o[7] = f2bf(a1.w);
    *(u16x8*)(out + (size_t)row * CDIM + ((gl ^ (row & 31)) * 8)) = o;
}

// ---------- Phase 1: MFMA GEMM + per-lane packed top-10 ----------
__device__ __forceinline__ void stage32(const unsigned short* __restrict__ htb,
                                        short* ldsbuf, int tbase, int Nt,
                                        int tid, int wbase) {
#pragma unroll
    for (int it = 0; it < 4; ++it) {
        int pp = it * 256 + tid;
        int rr = pp >> 5, gg = pp & 31;
        int grow = tbase + rr; grow = grow < Nt ? grow : Nt - 1;
        GLD_LDS(htb + (size_t)grow * CDIM + gg * 8, ldsbuf + (it * 256 + wbase) * 8);
    }
}

// block = 256 thr = 4 waves; wave w owns 32 s-cols (block spans 128 s).
// LDS: 2 x (32 t-rows x 256 bf16) = 32 KB double buffer.
__global__ __launch_bounds__(256, 3) void topk_mfma(
    const float* __restrict__ ehs, const float* __restrict__ rhs_,
    const unsigned short* __restrict__ ehtb, const unsigned short* __restrict__ rhtb,
    unsigned* __restrict__ partials, int Ns, int Nt, int Pt, int SB, int PS,
    unsigned VMASK)
{
    __shared__ short ldsT[2 * 32 * 256];

    const int tid = threadIdx.x;
    const int w = tid >> 6, lane = tid & 63;
    const int l5 = lane & 31, hi = lane >> 5;
    const int wbase = tid & ~63;
    const int CH = 2 * Pt;

    const int bid  = blockIdx.x;
    const int prob = bid / (Pt * SB);
    const int rem  = bid % (Pt * SB);
    const int p    = rem / SB, sb = rem % SB;

    const float* hs = prob ? rhs_ : ehs;
    const unsigned short* htb = prob ? rhtb : ehtb;

    const int srow = sb * 128 + w * 32 + l5;
    const int srd  = srow < Ns ? srow : Ns - 1;

    // B-panel: h_s[srd][kk*16 + hi*8 + j], j=0..7 -> 16 frags (64 regs), persistent.
    bf16x8 b[16];
#pragma unroll
    for (int kk = 0; kk < 16; ++kk) {
        const float4* sp = (const float4*)(hs + (size_t)srd * CDIM + kk * 16 + hi * 8);
        float4 f0 = sp[0], f1 = sp[1];
        bf16x8 t;
        t[0] = (short)f2bf(f0.x); t[1] = (short)f2bf(f0.y);
        t[2] = (short)f2bf(f0.z); t[3] = (short)f2bf(f0.w);
        t[4] = (short)f2bf(f1.x); t[5] = (short)f2bf(f1.y);
        t[6] = (short)f2bf(f1.z); t[7] = (short)f2bf(f1.w);
        b[kk] = t;
    }

    const int t0 = p * PS;
    const int t1 = min(t0 + PS, Nt);

    unsigned tvp[K_TOP];
#pragma unroll
    for (int q = 0; q < K_TOP; ++q) tvp[q] = 0u;

    const int rounds = (t1 > t0) ? ((t1 - t0 + 31) >> 5) : 0;

    if (rounds > 0) {
        stage32(htb, ldsT, t0, Nt, tid, wbase);
        __syncthreads();

        for (int rd = 0; rd < rounds; ++rd) {
            const int cur = rd & 1;
            const int tb  = t0 + rd * 32;
            if (rd + 1 < rounds)
                stage32(htb, ldsT + (cur ^ 1) * 8192, tb + 32, Nt, tid, wbase);

            const bool guard = (tb + 32 > t1);
            const short* rowp = ldsT + cur * 8192 + l5 * CDIM;
            // single acc chain; +256 pack bias via C-init (free vs zero-init).
            f32x16 acc;
#pragma unroll
            for (int r = 0; r < 16; ++r) acc[r] = 256.0f;
#pragma unroll
            for (int kk = 0; kk < 16; ++kk) {
                bf16x8 a = *(const bf16x8*)(rowp + (((kk * 2 + hi) ^ l5) * 8));
                acc = __builtin_amdgcn_mfma_f32_32x32x16_bf16(a, b[kk], acc, 0, 0, 0);
            }
            // ---- packed scan: one s-col per lane, 16 t-values ----
            const unsigned ibase = (unsigned)(rd << 4);
            unsigned pu[16];
#pragma unroll
            for (int r = 0; r < 16; ++r)
                pu[r] = (__float_as_uint(acc[r]) & VMASK) | (ibase + (unsigned)r);
            if (guard) {
#pragma unroll
                for (int r = 0; r < 16; ++r) {
                    int t = tb + 4 * hi + (r & 3) + 8 * (r >> 2);
                    if (t >= t1) pu[r] = 0u;
                }
            }
            unsigned mx = umax16(pu);
            while (__any((int)(mx > tvp[K_TOP - 1]))) {
                sorted_insert<K_TOP>(tvp, mx);   // no-op for lanes with mx <= tvp[9]
#pragma unroll
                for (int r = 0; r < 16; ++r)
                    pu[r] = (pu[r] == mx) ? 0u : pu[r];
                mx = umax16(pu);
            }
            __syncthreads();
        }
    }

    // chain write: RAW keys, layout [prob][chain][q][Ns], coalesced across srow
    if (srow < Ns) {
        unsigned* wp = partials + ((size_t)(prob * CH + (p * 2 + hi)) * K_TOP) * Ns + srow;
#pragma unroll
        for (int q = 0; q < K_TOP; ++q) wp[(size_t)q * Ns] = tvp[q];
    }
}

// ---------- Phase 2+3 fused: merge (wave-parallel) + f64 refine, one block/row ----------
// Merge: lane c (< CH) holds its chain's 10 DESC-sorted keys in named regs;
// CAND_M iterations of {wave-max butterfly, ballot-pick owner, owner decodes t
// into LDS and pops via static shift}. Then refine as before (t from LDS).
__global__ __launch_bounds__(256) void topk_refine(
    const float* __restrict__ ehs, const float* __restrict__ eht,
    const float* __restrict__ rhs_, const float* __restrict__ rht,
    const unsigned* __restrict__ partials, float* __restrict__ out,
    int Ns, int CH, int PS, unsigned rdMask)
{
    __shared__ double svd[CAND_M];
    __shared__ int    sci[CAND_M];

    const int wid = blockIdx.x;               // one row per block, grid = 2*Ns
    const int tid = threadIdx.x;
    const int m = tid >> 4, c16 = tid & 15;

    const int prob = wid < Ns ? 0 : 1;
    const int row  = prob ? (wid - Ns) : wid;
    const float* hs = prob ? rhs_ : ehs;
    const float* ht = prob ? rht  : eht;

    if (tid < CAND_M) sci[tid] = 0;           // wave-0 write, ordered before merge

    if (tid < 64) {
        const int c = tid;
        const unsigned* src = partials + ((size_t)prob * CH * K_TOP) * Ns + row;
        unsigned k0 = 0, k1 = 0, k2 = 0, k3 = 0, k4 = 0,
                 k5 = 0, k6 = 0, k7 = 0, k8 = 0, k9 = 0;
        if (c < CH) {
            const size_t stride = (size_t)Ns;
            const unsigned* cp = src + (size_t)c * K_TOP * Ns + row - row; // base
            cp = src + (size_t)(c * K_TOP) * Ns;
            k0 = cp[0 * stride]; k1 = cp[1 * stride]; k2 = cp[2 * stride];
            k3 = cp[3 * stride]; k4 = cp[4 * stride]; k5 = cp[5 * stride];
            k6 = cp[6 * stride]; k7 = cp[7 * stride]; k8 = cp[8 * stride];
            k9 = cp[9 * stride];
        }
        const int tbase = (c >> 1) * PS + 4 * (c & 1);
#pragma unroll
        for (int i = 0; i < CAND_M; ++i) {
            unsigned mx = k0;
            mx = umax2(mx, (unsigned)__shfl_xor((int)mx, 1,  64));
            mx = umax2(mx, (unsigned)__shfl_xor((int)mx, 2,  64));
            mx = umax2(mx, (unsigned)__shfl_xor((int)mx, 4,  64));
            mx = umax2(mx, (unsigned)__shfl_xor((int)mx, 8,  64));
            mx = umax2(mx, (unsigned)__shfl_xor((int)mx, 16, 64));
            mx = umax2(mx, (unsigned)__shfl_xor((int)mx, 32, 64));
            unsigned long long ball = __ballot(k0 == mx && c < CH);
            int owner = (int)__ffsll((unsigned long long)ball) - 1;
            if (tid == owner) {
                unsigned rd = (mx >> 4) & rdMask;
                unsigned r  = mx & 15u;
                sci[i] = tbase + (int)rd * 32 + (int)((r & 3) + 8 * (r >> 2));
                k0 = k1; k1 = k2; k2 = k3; k3 = k4; k4 = k5;
                k5 = k6; k6 = k7; k7 = k8; k8 = k9; k9 = 0u;
            }
        }
    }
    __syncthreads();

    // ---- f64 refine: candidate m (tid>>4), chunk c16 (tid&15) ----
    if (m < CAND_M) {
        const int t = sci[m];
        const float4* ap = (const float4*)(hs + (size_t)row * CDIM);
        const float4* bp = (const float4*)(ht + (size_t)t   * CDIM);

        double s = 0.0;
#pragma unroll
        for (int i = 0; i < 4; ++i) {
            float4 av = ap[c16 + 16 * i];
            float4 bv = bp[c16 + 16 * i];
            s += (double)av.x * (double)bv.x + (double)av.y * (double)bv.y
               + (double)av.z * (double)bv.z + (double)av.w * (double)bv.w;
        }
        s += __shfl_xor(s, 1, 64);
        s += __shfl_xor(s, 2, 64);
        s += __shfl_xor(s, 4, 64);
        s += __shfl_xor(s, 8, 64);            // 16-lane group: full dot for cand m
        if (c16 == 0) svd[m] = s;
    }
    __syncthreads();

    if (tid < 16) {                           // all 16 lanes run the butterfly
        const bool act = tid < CAND_M;
        const double sm = act ? svd[tid] : -1.0e300;
        const int    tm = act ? sci[tid] : 0x7FFFFFFF;
        int rank = 0; double vmax = -1.0e300;
#pragma unroll
        for (int j = 0; j < CAND_M; ++j) {
            double vj = svd[j]; int cj = sci[j];
            bool better = (vj > sm) || (vj == sm && cj < tm);
            rank += better ? 1 : 0;
            vmax = fmax(vmax, vj);
        }
        float ex = (act && rank < K_TOP) ? __expf((float)(sm - vmax)) : 0.f;
        float ssum = ex;
        ssum += __shfl_xor(ssum, 1, 64);
        ssum += __shfl_xor(ssum, 2, 64);
        ssum += __shfl_xor(ssum, 4, 64);
        ssum += __shfl_xor(ssum, 8, 64);      // sum over the 16 lanes (inactive = 0)
        if (act && rank < K_TOP) {
            size_t nsk = (size_t)Ns * K_TOP;
            size_t so  = (size_t)wid * K_TOP;
            out[so + rank] = ex / ssum;
            out[2 * nsk + so + rank] = (float)tm;
        }
    }
}

extern "C" void kernel_launch(void* const* d_in, const int* in_sizes, int n_in,
                              void* d_out, int out_size, void* d_ws, size_t ws_size,
                              hipStream_t stream) {
    (void)n_in; (void)out_size;
    const float* eh_s = (const float*)d_in[0];
    const float* eh_t = (const float*)d_in[1];
    const float* rh_s = (const float*)d_in[2];
    const float* rh_t = (const float*)d_in[3];
    // d_in[4] is k (=10), compile-time constant here.

    const int Ns = in_sizes[0] / CDIM;
    const int Nt = in_sizes[1] / CDIM;
    const int SB = (Ns + 127) / 128;

    const size_t htbElems = (size_t)Nt * CDIM;          // per array, ushorts
    const size_t htbBytes = 2 * htbElems * 2;

    // Pt=14: 2212 blocks. r9 showed larger Pt replicates the B-panel prologue
    // (+60 MB fetch, +15 us). PS=736 -> up to 23 rounds. CH = 2*Pt <= 64 (merge
    // assumes one chain per lane).
    int Pt = 14;
    while (Pt > 1 &&
           htbBytes + (size_t)2 * Ns * (2 * Pt) * K_TOP * sizeof(unsigned) > ws_size)
        Pt -= 1;
    const int PS = (int)((((size_t)Nt + Pt - 1) / Pt + 31) & ~(size_t)31);

    // idx-field width: 4 (r) + rdbits, where 2^rdbits >= PS/32. VMASK keeps the rest.
    int rdbits = 0;
    while ((1 << rdbits) < (PS >> 5)) ++rdbits;
    const int IDXB = 4 + rdbits;
    const unsigned VMASK  = ~((1u << IDXB) - 1u);
    const unsigned rdMask = (1u << rdbits) - 1u;

    unsigned short* htb_e = (unsigned short*)d_ws;
    unsigned short* htb_r = htb_e + htbElems;
    unsigned* partials = (unsigned*)(htb_r + htbElems);

    dim3 block(256);

    // Phase 0: convert both h_t arrays (swizzled bf16), one dispatch
    int convBlocks = (2 * Nt * 32 + 255) / 256;
    conv_swz2<<<dim3(convBlocks), block, 0, stream>>>(eh_t, htb_e, rh_t, htb_r, Nt);

    // Phase 1: MFMA GEMM + packed top-10 chains
    topk_mfma<<<dim3(2 * Pt * SB), block, 0, stream>>>(eh_s, rh_s, htb_e, htb_r,
                                                       partials, Ns, Nt, Pt, SB, PS,
                                                       VMASK);

    // Phase 2+3 fused: merge + f64 refine + softmax + write (one block per row)
    int nrows = 2 * Ns;
    topk_refine<<<dim3(nrows), block, 0, stream>>>(eh_s, eh_t, rh_s, rh_t,
                                                   partials, (float*)d_out,
                                                   Ns, 2 * Pt, PS, rdMask);
}